// Round 5
// baseline (543.759 us; speedup 1.0000x reference)
//
#include <hip/hip_runtime.h>
#include <math.h>

#define NN 100000
#define NE 3200000
#define INF_ 256
#define NH 8
#define OF 64
#define EF 64
#define NT 8

#define BSH 7                  // log2(nodes per bucket)
#define BNODES 128             // nodes per bucket
#define NB 782                 // ceil(NN/128)
#define CAPB 4608              // slots/bucket: Poisson(4096)+8 sigma
#define SPLIT 4                // sub-blocks per bucket in k_bucket_sum
#define EPB 8192               // edges per k_partition block (doubled: 2x write-burst length)

typedef float vf4 __attribute__((ext_vector_type(4)));

// ws layout (float units). el separated from ers so the 3.2MB el table fits per-XCD L2;
// ers[n] = {er[0..7], s[0..7]} shares one 64B line (K4 gathers er+s in ONE line).
// s-columns are zeroed by k_node and accumulated by k_bucket_sum via global atomicAdd.
static constexpr size_t WS_AT      = 0;                        // 4096
static constexpr size_t WS_EE      = 4096;                     // 64
static constexpr size_t WS_EL      = 4160;                     // NN*8
static constexpr size_t WS_ERS     = WS_EL + (size_t)NN * 8;   // NN*16 (64B-aligned)
static constexpr size_t WS_CCNT    = WS_ERS + (size_t)NN * 16; // NB
static constexpr size_t WS_PART    = WS_CCNT + NB + 2;         // NB*CAPB u32

// K1 (fused preps): blocks 0..15: At[c][i] = sum_o W_fc[i, h*64+o]*attn[h,o]
// (c<8->attn_l else attn_r) + ccnt zeroing. Block 16: ee_tab[t][h].
__global__ __launch_bounds__(256) void k_prep(const float* __restrict__ W_fc,
                                              const float* __restrict__ attn_l,
                                              const float* __restrict__ attn_r,
                                              const float* __restrict__ edge_emb,
                                              const float* __restrict__ W_e,
                                              const float* __restrict__ attn_e,
                                              float* __restrict__ At,
                                              float* __restrict__ ee_tab,
                                              unsigned* __restrict__ ccnt) {
    if (blockIdx.x < 16) {
        int t = blockIdx.x * 256 + threadIdx.x;   // 0..4095
        if (t < NB) ccnt[t] = 0u;
        int c = t >> 8;
        int i = t & 255;
        int h = c & 7;
        const float* attn = (c < 8) ? attn_l : attn_r;
        const float* wrow = W_fc + (size_t)i * (NH * OF) + h * OF;
        const float* arow = attn + h * OF;
        float acc = 0.f;
#pragma unroll 8
        for (int o = 0; o < OF; ++o) acc += wrow[o] * arow[o];
        At[c * INF_ + i] = acc;
    } else {
        __shared__ float B[EF][NH];
        int t = threadIdx.x;
#pragma unroll
        for (int p = 0; p < 2; ++p) {
            int idx = t + p * 256;                // 0..511
            int g = idx >> 3, h = idx & 7;
            const float* wrow = W_e + (size_t)g * (NH * EF) + h * EF;
            const float* arow = attn_e + h * EF;
            float acc = 0.f;
#pragma unroll 8
            for (int f = 0; f < EF; ++f) acc += wrow[f] * arow[f];
            B[g][h] = acc;
        }
        __syncthreads();
        if (t < NT * NH) {
            int tt = t >> 3, hh = t & 7;
            float a = 0.f;
#pragma unroll 8
            for (int g2 = 0; g2 < EF; ++g2) a += edge_emb[tt * EF + g2] * B[g2][hh];
            ee_tab[tt * NH + hh] = a;
        }
    }
}

// K2: el[n][h], ers[n][0..7]=er, ers[n][8..15]=0 (s accumulator init).
// feat is read-once -> non-temporal (keep L2 for el/ers/part used downstream).
__global__ __launch_bounds__(256) void k_node(const float* __restrict__ feat,
                                              const float* __restrict__ At,
                                              float* __restrict__ el,
                                              float* __restrict__ ers) {
    int n = blockIdx.x * 256 + threadIdx.x;
    if (n >= NN) return;
    const vf4* f4 = (const vf4*)(feat + (size_t)n * INF_);
    const float4* A4 = (const float4*)At;
    float acc[16];
#pragma unroll
    for (int c = 0; c < 16; ++c) acc[c] = 0.f;
    for (int iq = 0; iq < INF_ / 4; ++iq) {
        vf4 f = __builtin_nontemporal_load(f4 + iq);
#pragma unroll
        for (int c = 0; c < 16; ++c) {
            float4 a = A4[c * 64 + iq];
            acc[c] += f.x * a.x + f.y * a.y + f.z * a.z + f.w * a.w;
        }
    }
    float4* e4 = (float4*)(el + (size_t)n * 8);
    e4[0] = make_float4(acc[0], acc[1], acc[2], acc[3]);
    e4[1] = make_float4(acc[4], acc[5], acc[6], acc[7]);
    float4* r4 = (float4*)(ers + (size_t)n * 16);
    r4[0] = make_float4(acc[8], acc[9], acc[10], acc[11]);
    r4[1] = make_float4(acc[12], acc[13], acc[14], acc[15]);
    r4[2] = make_float4(0.f, 0.f, 0.f, 0.f);
    r4[3] = make_float4(0.f, 0.f, 0.f, 0.f);
}

// K3a: partition into NB buckets. EPB=8192: per-bucket write bursts avg 10.4
// consecutive u32 (~83B) vs 5.2 at 4096 -> scattered line-RMWs per edge halved;
// hist/cursor prologue amortized 2x. idx streams read-once -> non-temporal.
__global__ __launch_bounds__(256) void k_partition(const int* __restrict__ src,
                                                   const int* __restrict__ dst,
                                                   const int* __restrict__ etype,
                                                   unsigned* __restrict__ ccnt,
                                                   unsigned* __restrict__ part) {
    __shared__ unsigned hist[NB];
    __shared__ unsigned cursor[NB];
    int tid = threadIdx.x;
    size_t base = (size_t)blockIdx.x * EPB;
    unsigned long long rc[32];
    for (int i = tid; i < NB; i += 256) hist[i] = 0u;
    __syncthreads();
#pragma unroll
    for (int k = 0; k < 32; ++k) {
        size_t j = base + (size_t)k * 256 + tid;
        if (j < NE) {
            int dj = __builtin_nontemporal_load(dst + j);
            int sj = __builtin_nontemporal_load(src + j);
            int tj = __builtin_nontemporal_load(etype + j);
            rc[k] = (unsigned long long)(unsigned)sj
                  | ((unsigned long long)(unsigned)tj << 17)
                  | ((unsigned long long)(unsigned)dj << 20);
            atomicAdd(&hist[dj >> BSH], 1u);
        } else rc[k] = ~0ull;
    }
    __syncthreads();
    for (int i = tid; i < NB; i += 256) {
        unsigned h = hist[i];
        cursor[i] = h ? atomicAdd(ccnt + i, h) : 0u;
    }
    __syncthreads();
#pragma unroll
    for (int k = 0; k < 32; ++k) {
        if (rc[k] == ~0ull) continue;
        int dj = (int)(rc[k] >> 20);
        int b = dj >> BSH;
        unsigned pos = atomicAdd(&cursor[b], 1u);
        if (pos < CAPB)
            part[(size_t)b * CAPB + pos] =
                (unsigned)(rc[k] & 0xFFFFFull) | ((unsigned)(dj & (BNODES - 1)) << 20);
    }
}

// K3b: per-sub-bucket sum — lane-per-edge (unchanged core; pinned at ~29 cyc/edge/CU
// across 4 structural rewrites). pp stream read-once -> non-temporal so el stays
// L2-resident.
__global__ __launch_bounds__(256) void k_bucket_sum(const unsigned* __restrict__ part,
                                                    const unsigned* __restrict__ ccnt,
                                                    const float* __restrict__ el,
                                                    const float* __restrict__ ers,
                                                    const float* __restrict__ ee_tab,
                                                    float* __restrict__ ers_out) {
    __shared__ float sbin[BNODES * 9];
    int bs = blockIdx.x;
    int b = bs >> 2, c = bs & 3;     // SPLIT=4
    int tid = threadIdx.x;
    int n0 = b << BSH;
    int nn = NN - n0; if (nn > BNODES) nn = BNODES;

    for (int i = tid; i < BNODES * 9; i += 256) sbin[i] = 0.f;
    __syncthreads();

    unsigned cnt = ccnt[b]; if (cnt > CAPB) cnt = CAPB;
    const unsigned* pp = part + (size_t)b * CAPB;
    for (unsigned e = (unsigned)(c * 256 + tid); e < cnt; e += 1024) {
        unsigned rec = __builtin_nontemporal_load(pp + e);
        int sj = (int)(rec & 0x1FFFFu);
        int et = (int)((rec >> 17) & 7u);
        int dl = (int)((rec >> 20) & (BNODES - 1));
        const float4* el4 = (const float4*)(el + (size_t)sj * 8);
        const float4* E   = (const float4*)(ers + (size_t)(n0 + dl) * 16);
        const float4* ee4 = (const float4*)(ee_tab + et * NH);
        float4 la = el4[0], lb = el4[1];
        float4 ra = E[0],   rb = E[1];
        float4 ea = ee4[0], eb = ee4[1];
        float* sb = &sbin[dl * 9];
        atomicAdd(&sb[0], __expf(fmaxf(la.x + ra.x + ea.x, 0.f)));
        atomicAdd(&sb[1], __expf(fmaxf(la.y + ra.y + ea.y, 0.f)));
        atomicAdd(&sb[2], __expf(fmaxf(la.z + ra.z + ea.z, 0.f)));
        atomicAdd(&sb[3], __expf(fmaxf(la.w + ra.w + ea.w, 0.f)));
        atomicAdd(&sb[4], __expf(fmaxf(lb.x + rb.x + eb.x, 0.f)));
        atomicAdd(&sb[5], __expf(fmaxf(lb.y + rb.y + eb.y, 0.f)));
        atomicAdd(&sb[6], __expf(fmaxf(lb.z + rb.z + eb.z, 0.f)));
        atomicAdd(&sb[7], __expf(fmaxf(lb.w + rb.w + eb.w, 0.f)));
    }
    __syncthreads();
    for (int i = tid; i < nn * NH; i += 256) {
        int nl = i >> 3, hh = i & 7;
        atomicAdd(&ers_out[(size_t)(n0 + nl) * 16 + 8 + hh], sbin[nl * 9 + hh]);
    }
}

// K4: out[j][h] = exp(e)/s. idx loads + out stores are non-temporal so the 140MB
// of streaming traffic does NOT evict the el (3.2MB) / ers (6.4MB) gather tables
// from the 4MB/XCD L2 — the random gathers are the latency wall here.
__global__ __launch_bounds__(256) void k_edge_out(const int* __restrict__ src,
                                                  const int* __restrict__ dst,
                                                  const int* __restrict__ etype,
                                                  const float* __restrict__ el,
                                                  const float* __restrict__ ers,
                                                  const float* __restrict__ ee_tab,
                                                  float* __restrict__ out) {
    int j = blockIdx.x * 256 + threadIdx.x;
    if (j >= NE) return;
    int sj = __builtin_nontemporal_load(src + j);
    int dj = __builtin_nontemporal_load(dst + j);
    int tj = __builtin_nontemporal_load(etype + j);
    const float4* el4 = (const float4*)(el + (size_t)sj * 8);
    const float4* E   = (const float4*)(ers + (size_t)dj * 16);
    const float4* ee4 = (const float4*)(ee_tab + tj * NH);
    float4 l0 = el4[0], l1 = el4[1];
    float4 r0 = E[0], r1 = E[1];
    float4 s0 = E[2], s1 = E[3];
    float4 e0 = ee4[0], e1 = ee4[1];
    vf4 o0, o1;
    o0.x = __expf(fmaxf(l0.x + r0.x + e0.x, 0.f)) / s0.x;
    o0.y = __expf(fmaxf(l0.y + r0.y + e0.y, 0.f)) / s0.y;
    o0.z = __expf(fmaxf(l0.z + r0.z + e0.z, 0.f)) / s0.z;
    o0.w = __expf(fmaxf(l0.w + r0.w + e0.w, 0.f)) / s0.w;
    o1.x = __expf(fmaxf(l1.x + r1.x + e1.x, 0.f)) / s1.x;
    o1.y = __expf(fmaxf(l1.y + r1.y + e1.y, 0.f)) / s1.y;
    o1.z = __expf(fmaxf(l1.z + r1.z + e1.z, 0.f)) / s1.z;
    o1.w = __expf(fmaxf(l1.w + r1.w + e1.w, 0.f)) / s1.w;
    vf4* o4 = (vf4*)(out + (size_t)j * NH);
    __builtin_nontemporal_store(o0, o4);
    __builtin_nontemporal_store(o1, o4 + 1);
}

extern "C" void kernel_launch(void* const* d_in, const int* in_sizes, int n_in,
                              void* d_out, int out_size, void* d_ws, size_t ws_size,
                              hipStream_t stream) {
    const float* feat     = (const float*)d_in[0];
    const int*   etype    = (const int*)d_in[1];
    const int*   src      = (const int*)d_in[2];
    const int*   dst      = (const int*)d_in[3];
    const float* W_fc     = (const float*)d_in[4];
    const float* edge_emb = (const float*)d_in[5];
    const float* W_e      = (const float*)d_in[6];
    const float* attn_l   = (const float*)d_in[7];
    const float* attn_r   = (const float*)d_in[8];
    const float* attn_e   = (const float*)d_in[9];

    float*    ws      = (float*)d_ws;
    float*    At      = ws + WS_AT;
    float*    ee_tab  = ws + WS_EE;
    float*    el      = ws + WS_EL;
    float*    ers     = ws + WS_ERS;
    unsigned* ccnt    = (unsigned*)(ws + WS_CCNT);
    unsigned* part    = (unsigned*)(ws + WS_PART);
    float*    out     = (float*)d_out;

    hipLaunchKernelGGL(k_prep, dim3(17), dim3(256), 0, stream,
                       W_fc, attn_l, attn_r, edge_emb, W_e, attn_e, At, ee_tab, ccnt);
    hipLaunchKernelGGL(k_node, dim3((NN + 255) / 256), dim3(256), 0, stream, feat, At, el, ers);
    hipLaunchKernelGGL(k_partition, dim3((NE + EPB - 1) / EPB), dim3(256), 0, stream,
                       src, dst, etype, ccnt, part);
    hipLaunchKernelGGL(k_bucket_sum, dim3(NB * SPLIT), dim3(256), 0, stream,
                       part, ccnt, el, ers, ee_tab, ers);
    hipLaunchKernelGGL(k_edge_out, dim3((NE + 255) / 256), dim3(256), 0, stream,
                       src, dst, etype, el, ers, ee_tab, out);
}